// Round 9
// baseline (315.714 us; speedup 1.0000x reference)
//
#include <hip/hip_runtime.h>
#include <hip/hip_bf16.h>

// Problem constants
#define FMAPS 128     // feature maps
#define SEQL  512     // L
#define BATCH 64      // B
#define EMB   300     // embedding dim (fp32 sentence row = 1200 B, 16B-aligned)
#define NROI  2048
#define FFDIM 512
#define NCLS  8
#define GRID  512     // 2 blocks/CU on 256 CUs -> all co-resident (proof in header comment)

typedef short bf16x8 __attribute__((ext_vector_type(8)));   // 8 bf16 (4 VGPRs)
typedef float f32x4  __attribute__((ext_vector_type(4)));   // MFMA accumulator

static __device__ __forceinline__ float relu_(float x) { return x > 0.f ? x : 0.f; }
static __device__ __forceinline__ uint bf16bits(float f) {
    __hip_bfloat16 h = __float2bfloat16(f);
    return (uint)*reinterpret_cast<ushort*>(&h);
}

// Hand-rolled grid barrier (generation-based, agent scope).
// SAFETY: requires all GRID blocks co-resident — proven: LDS 42.25KB -> 3 blocks/CU
// capacity, launch_bounds(256,2) caps VGPR at 256 -> 8 waves/CU OK; grid = 256CU x 2.
// bar[0]=cnt, bar[1]=gen, both zeroed via hipMemsetAsync before launch.
static __device__ __forceinline__ void grid_barrier(uint* bar, int tid) {
    __syncthreads();
    if (tid == 0) {
        __threadfence();   // make this block's global writes visible (agent scope)
        uint g = __hip_atomic_load(bar + 1, __ATOMIC_RELAXED, __HIP_MEMORY_SCOPE_AGENT);
        uint a = __hip_atomic_fetch_add(bar, 1u, __ATOMIC_ACQ_REL, __HIP_MEMORY_SCOPE_AGENT);
        if (a == GRID - 1) {
            // reset cnt BEFORE the release-store of gen: re-arrivals at the next
            // barrier observe cnt=0 via acquire(gen) happens-before.
            __hip_atomic_store(bar, 0u, __ATOMIC_RELAXED, __HIP_MEMORY_SCOPE_AGENT);
            __hip_atomic_store(bar + 1, g + 1u, __ATOMIC_RELEASE, __HIP_MEMORY_SCOPE_AGENT);
        } else {
            while (__hip_atomic_load(bar + 1, __ATOMIC_ACQUIRE, __HIP_MEMORY_SCOPE_AGENT) == g) {
                __builtin_amdgcn_s_sleep(8);
            }
        }
        __threadfence();   // acquire side: invalidate caches before reading others' writes
    }
    __syncthreads();
}

// ---------------------------------------------------------------------------
// Single fused kernel, 512 blocks x 256 threads, 3 phases (R5-verified bodies):
//  P1: Wf fragment build (240 elems/block);
//      blocks 0-63: Mf partials (c=blk&7, q8=blk>>3, 64 i-rows each); block 64: b2.
//  P2: conv as MFMA GEMM: 64(M)x128(N) tile/block, LDS-staged A
//      (66 rows x 320 bf16, XOR-swizzled), direct-global B fragments.
//  P3: ROI max-pool + collapsed FC (4 ROIs/block, 8-partial Mf sum).
// ---------------------------------------------------------------------------
__global__ __launch_bounds__(256, 2) void rcnn_fused(
    const float* __restrict__ sent, const int* __restrict__ rois,
    const int* __restrict__ ridx, const float* __restrict__ conv_w,
    const float* __restrict__ cb, const float* __restrict__ cls_w,
    const float* __restrict__ fc1_w, const float* __restrict__ fc1_b,
    const float* __restrict__ cls_b,
    ushort* __restrict__ wf, float* __restrict__ Mfp, float* __restrict__ b2,
    float* __restrict__ feat, float* __restrict__ out, uint* __restrict__ bar) {
    __shared__ __align__(16) ushort XL[66 * 320];   // 42240 B (reused as red[] in P1)
    const int t   = threadIdx.x;
    const int blk = blockIdx.x;

    // ================= Phase 1: prep =================
    if (t < 240) {   // Wf: idx = blk*240 + t covers 512*240 = 122880 exactly
        int idx  = blk * 240 + t;
        int j    = idx & 7;
        int lane = (idx >> 3) & 63;
        int nt   = (idx >> 9) & 7;
        int kc   = idx >> 12;
        int f = nt * 16 + (lane & 15);
        int k = kc * 32 + (lane >> 4) * 8 + j;
        int kr = k / 320, d = k % 320;
        float v = (d < EMB) ? conv_w[f * 900 + kr * 300 + d] : 0.f;
        wf[idx] = (ushort)bf16bits(v);
    }
    if (blk < 64) {          // Mf partial: Mfp[(q8*8+c)][g]
        float* red = (float*)XL;            // 256 floats
        const int c = blk & 7, q8 = blk >> 3;
        const int g = t & 127, ih = t >> 7;
        const int i0 = q8 * 64 + ih * 32;
        float s = 0.f;
        for (int i = i0; i < i0 + 32; ++i) {
            float4 w4 = *(const float4*)(fc1_w + (size_t)i * FFDIM + 4 * g);
            s = fmaf(cls_w[c * FFDIM + i], (w4.x + w4.y) + (w4.z + w4.w), s);
        }
        red[ih * 128 + g] = s;
        __syncthreads();
        if (t < 128) Mfp[(q8 * 8 + c) * FMAPS + t] = red[t] + red[128 + t];
    } else if (blk == 64) {  // b2
        const int c = t >> 5, l32 = t & 31;
        float s = 0.f;
        for (int i = l32; i < FFDIM; i += 32)
            s = fmaf(cls_w[c * FFDIM + i], fc1_b[i], s);
#pragma unroll
        for (int off = 16; off; off >>= 1) s += __shfl_xor(s, off, 64);
        if (l32 == 0) b2[c] = s + cls_b[c];
    }
    grid_barrier(bar, t);

    // ================= Phase 2: conv =================
    {
        const int lane = t & 63;
        const int wn   = t >> 6;            // N quarter: cols wn*32..+31
        const int b    = blk >> 3;
        const int l0   = (blk & 7) << 6;
        const int mrow = lane & 15;
        const int koct = lane >> 4;

        // stage 2640 chunks (row j = c/40, 16B-block i16 = c%40), XOR-swizzled
#pragma unroll
        for (int it = 0; it < 11; ++it) {
            int c = it * 256 + t;
            if (c < 2640) {
                int j = c / 40, i16 = c - j * 40;
                int sr = l0 + j - 1;                       // sentence row (pad: -1, 512)
                int d0 = i16 * 8;
                float4 va = make_float4(0.f, 0.f, 0.f, 0.f), vb = va;
                if ((unsigned)sr < (unsigned)SEQL) {
                    const float* srow = sent + ((size_t)b * SEQL + sr) * EMB;
                    if (d0 < EMB)     va = *(const float4*)(srow + d0);
                    if (d0 + 4 < EMB) vb = *(const float4*)(srow + d0 + 4);
                }
                uint4 pk;
                pk.x = bf16bits(va.x) | (bf16bits(va.y) << 16);
                pk.y = bf16bits(va.z) | (bf16bits(va.w) << 16);
                pk.z = bf16bits(vb.x) | (bf16bits(vb.y) << 16);
                pk.w = bf16bits(vb.z) | (bf16bits(vb.w) << 16);
                *(uint4*)((char*)XL + j * 640 + ((i16 ^ (j & 7)) << 4)) = pk;
            }
        }
        __syncthreads();

        f32x4 acc[4][2] = {};
        const ushort* wlane = wf + (size_t)(wn * 2) * 512 + (size_t)lane * 8;

#pragma unroll
        for (int kr = 0; kr < 3; ++kr) {
            const int sj = (mrow + kr) & 7;       // (j&7), mr*16 ≡ 0 mod 8
#pragma unroll
            for (int dc = 0; dc < 10; ++dc) {
                const int kc = kr * 10 + dc;
                bf16x8 a[4];
#pragma unroll
                for (int mr = 0; mr < 4; ++mr) {
                    const int j = mr * 16 + mrow + kr;
                    a[mr] = *(const bf16x8*)((const char*)XL + j * 640 +
                                             (((dc * 4 + koct) ^ sj) << 4));
                }
                const ushort* wk = wlane + (size_t)kc * 4096;
                bf16x8 b0 = *(const bf16x8*)(wk);
                bf16x8 b1 = *(const bf16x8*)(wk + 512);
#pragma unroll
                for (int mr = 0; mr < 4; ++mr) {
                    acc[mr][0] = __builtin_amdgcn_mfma_f32_16x16x32_bf16(a[mr], b0, acc[mr][0], 0, 0, 0);
                    acc[mr][1] = __builtin_amdgcn_mfma_f32_16x16x32_bf16(a[mr], b1, acc[mr][1], 0, 0, 0);
                }
            }
        }

        // epilogue: C/D layout col=lane&15, row=(lane>>4)*4+r [m91-verified]
#pragma unroll
        for (int nr = 0; nr < 2; ++nr) {
            const int f = wn * 32 + nr * 16 + mrow;
            const float bias = cb[f];
#pragma unroll
            for (int mr = 0; mr < 4; ++mr) {
                const int lb = l0 + mr * 16 + koct * 4;
#pragma unroll
                for (int r = 0; r < 4; ++r)
                    feat[((size_t)b * SEQL + (lb + r)) * FMAPS + f] = relu_(acc[mr][nr][r] + bias);
            }
        }
    }
    grid_barrier(bar, t);

    // ================= Phase 3: ROI pool + FC =================
    {
        const int w    = t >> 6;
        const int lane = t & 63;
        const int n    = blk * 4 + w;          // 512*4 = 2048 ROIs
        const int x1 = rois[n * 2 + 0];
        const int x2 = rois[n * 2 + 1];
        const int bi = ridx[n];
        const int half = lane >> 5, c4 = lane & 31;

        const float* base = feat + (size_t)bi * SEQL * FMAPS + c4 * 4;
        float4 m = make_float4(-1e30f, -1e30f, -1e30f, -1e30f);
        for (int l = x1 + half; l < x2; l += 2) {
            float4 v = *(const float4*)(base + (size_t)l * FMAPS);
            m.x = fmaxf(m.x, v.x); m.y = fmaxf(m.y, v.y);
            m.z = fmaxf(m.z, v.z); m.w = fmaxf(m.w, v.w);
        }
        m.x = fmaxf(m.x, __shfl_xor(m.x, 32, 64));
        m.y = fmaxf(m.y, __shfl_xor(m.y, 32, 64));
        m.z = fmaxf(m.z, __shfl_xor(m.z, 32, 64));
        m.w = fmaxf(m.w, __shfl_xor(m.w, 32, 64));

        const float4* M4 = (const float4*)Mfp;     // [(q8*8+c)*32 + c4]
#pragma unroll
        for (int c = 0; c < 8; ++c) {
            float4 wv = make_float4(0.f, 0.f, 0.f, 0.f);
#pragma unroll
            for (int q = 0; q < 8; ++q) {
                float4 wq = M4[(q * 8 + c) * 32 + c4];
                wv.x += wq.x; wv.y += wq.y; wv.z += wq.z; wv.w += wq.w;
            }
            float p = m.x * wv.x + m.y * wv.y + m.z * wv.z + m.w * wv.w;
#pragma unroll
            for (int off = 16; off; off >>= 1) p += __shfl_xor(p, off, 64);
            if (lane == 0) out[n * NCLS + c] = p + b2[c];
        }
    }
}

// ---------------------------------------------------------------------------
extern "C" void kernel_launch(void* const* d_in, const int* in_sizes, int n_in,
                              void* d_out, int out_size, void* d_ws, size_t ws_size,
                              hipStream_t stream) {
    const float* sentence = (const float*)d_in[0];
    const int*   rois     = (const int*)d_in[1];
    const int*   ridx     = (const int*)d_in[2];
    const float* conv_w   = (const float*)d_in[3];
    const float* conv_b   = (const float*)d_in[4];
    const float* fc1_w    = (const float*)d_in[5];
    const float* fc1_b    = (const float*)d_in[6];
    const float* cls_w    = (const float*)d_in[7];
    const float* cls_b    = (const float*)d_in[8];
    float* out = (float*)d_out;

    // workspace carve-up (bytes)
    char* ws = (char*)d_ws;
    float*  Ft  = (float*)ws;                          // 64*512*128 f32 = 16,777,216 B
    ushort* Wf  = (ushort*)(ws + 16777216);            // 122,880 bf16  = 245,760 B
    float*  Mfp = (float*)(ws + 16777216 + 245760);    // 64*128 f32    = 32,768 B
    float*  b2  = Mfp + 8192;                          // 8 f32 (+ pad to 256 B)
    uint*   bar = (uint*)(ws + 16777216 + 245760 + 32768 + 256);   // cnt, gen

    hipMemsetAsync(bar, 0, 16, stream);
    hipLaunchKernelGGL(rcnn_fused, dim3(GRID), dim3(256), 0, stream,
                       sentence, rois, ridx, conv_w, conv_b, cls_w,
                       fc1_w, fc1_b, cls_b, Wf, Mfp, b2, Ft, out, bar);
}

// Round 12
// 123.371 us; speedup vs baseline: 2.5591x; 2.5591x over previous
//
#include <hip/hip_runtime.h>
#include <hip/hip_bf16.h>

// Problem constants
#define FMAPS 128     // feature maps
#define SEQL  512     // L
#define BATCH 64      // B
#define EMB   300     // embedding dim (fp32 sentence row = 1200 B, 16B-aligned)
#define NROI  2048
#define FFDIM 512
#define NCLS  8

// prep grid carve-up (R5-verified): Mf partial blocks first, then b2, then Wf.
#define MF_BLOCKS   32     // 8 classes x 4 K-quarters -> deterministic partials
#define B2_BLOCKS   1
#define WPAD_BLOCKS 480    // 30*8*64*8 / 256

typedef short  bf16x8 __attribute__((ext_vector_type(8)));   // 8 bf16 (4 VGPRs)
typedef float  f32x4  __attribute__((ext_vector_type(4)));   // MFMA accumulator
typedef ushort u16x8  __attribute__((ext_vector_type(8)));   // 8 bf16 bit patterns

static __device__ __forceinline__ float relu_(float x) { return x > 0.f ? x : 0.f; }
static __device__ __forceinline__ uint bf16bits(float f) {
    __hip_bfloat16 h = __float2bfloat16(f);
    return (uint)*reinterpret_cast<ushort*>(&h);
}
static __device__ __forceinline__ u16x8 umax8(u16x8 a, u16x8 b) {
    u16x8 r;
#pragma unroll
    for (int j = 0; j < 8; ++j) r[j] = a[j] > b[j] ? a[j] : b[j];
    return r;
}
static __device__ __forceinline__ u16x8 shfl8(u16x8 a, int off) {
    union { u16x8 v; int i[4]; } s; s.v = a;
#pragma unroll
    for (int k = 0; k < 4; ++k) s.i[k] = __shfl_xor(s.i[k], off, 64);
    return s.v;
}

// ---------------------------------------------------------------------------
// 1. prep (R5-verified, unchanged):
//    [0,32)  : Mfp[q*8+c][g] = sum_{i in q-quarter} cls_w[c][i]*sum_p fc1_w[i][4g+p]
//    [32]    : b2[c] = cls_b[c] + cls_w[c]·fc1_b
//    [33,513): conv_w -> WF fragment-major bf16
// ---------------------------------------------------------------------------
__global__ __launch_bounds__(256) void prep(
    const float* __restrict__ conv_w, const float* __restrict__ cls_w,
    const float* __restrict__ fc1_w, const float* __restrict__ fc1_b,
    const float* __restrict__ cls_b,
    ushort* __restrict__ wf, float* __restrict__ Mfp, float* __restrict__ b2) {
    __shared__ float red[2][128];
    const int tid = threadIdx.x;
    int blk = blockIdx.x;

    if (blk < MF_BLOCKS) {
        const int c = blk & 7, q = blk >> 3;
        const int g = tid & 127, ih = tid >> 7;
        const int i0 = q * 128 + ih * 64;
        float s = 0.f;
        for (int i = i0; i < i0 + 64; ++i) {
            float4 w4 = *(const float4*)(fc1_w + (size_t)i * FFDIM + 4 * g);
            s = fmaf(cls_w[c * FFDIM + i], (w4.x + w4.y) + (w4.z + w4.w), s);
        }
        red[ih][g] = s;
        __syncthreads();
        if (tid < 128) Mfp[(q * 8 + c) * FMAPS + tid] = red[0][tid] + red[1][tid];
        return;
    }
    blk -= MF_BLOCKS;

    if (blk < B2_BLOCKS) {
        const int c = tid >> 5, l32 = tid & 31;
        float s = 0.f;
        for (int i = l32; i < FFDIM; i += 32)
            s = fmaf(cls_w[c * FFDIM + i], fc1_b[i], s);
#pragma unroll
        for (int off = 16; off; off >>= 1) s += __shfl_xor(s, off, 64);
        if (l32 == 0) b2[c] = s + cls_b[c];
        return;
    }
    blk -= B2_BLOCKS;

    {   // Wf build
        int idx = blk * 256 + tid;                 // < 122,880 exactly
        int j    = idx & 7;
        int lane = (idx >> 3) & 63;
        int nt   = (idx >> 9) & 7;
        int kc   = idx >> 12;
        int f = nt * 16 + (lane & 15);
        int k = kc * 32 + (lane >> 4) * 8 + j;
        int kr = k / 320, d = k % 320;
        float v = (d < EMB) ? conv_w[f * 900 + kr * 300 + d] : 0.f;
        wf[idx] = (ushort)bf16bits(v);
    }
}

// ---------------------------------------------------------------------------
// 2. Conv as MFMA GEMM v4: M-tile 32 (was 64) for 2x occupancy.
//    Block: 256 thr = 4 waves, tile 32(M) x 128(N); wave = 32x32 (Mr=2, Nr=2).
//    Grid 1024 -> 4 blocks/CU -> 4 waves/SIMD.
//    LDS: 34 rows x 320 bf16 (640 B/row) = 21760 B, XOR-swizzled (i16 ^= j&7).
//    Output feat is bf16 (ushort bits).
// ---------------------------------------------------------------------------
__global__ __launch_bounds__(256, 4) void conv_mfma(
    const float* __restrict__ sent, const ushort* __restrict__ wf,
    const float* __restrict__ cb, ushort* __restrict__ feat) {
    __shared__ __align__(16) ushort XL[34 * 320];   // 21760 B
    const int t    = threadIdx.x;
    const int lane = t & 63;
    const int wn   = t >> 6;            // N quarter: cols wn*32..+31
    const int b    = blockIdx.x >> 4;
    const int l0   = (blockIdx.x & 15) << 5;
    const int mrow = lane & 15;
    const int koct = lane >> 4;

    // ---- stage 1360 chunks (row j = c/40, 16B-block i16 = c%40), swizzled ----
#pragma unroll
    for (int it = 0; it < 6; ++it) {
        int c = it * 256 + t;
        if (c < 1360) {
            int j = c / 40, i16 = c - j * 40;
            int sr = l0 + j - 1;                       // sentence row (pad: -1, 512)
            int d0 = i16 * 8;
            float4 va = make_float4(0.f, 0.f, 0.f, 0.f), vb = va;
            if ((unsigned)sr < (unsigned)SEQL) {
                const float* srow = sent + ((size_t)b * SEQL + sr) * EMB;
                if (d0 < EMB)     va = *(const float4*)(srow + d0);      // d0<=296
                if (d0 + 4 < EMB) vb = *(const float4*)(srow + d0 + 4);  // d0<=292
            }
            uint4 pk;
            pk.x = bf16bits(va.x) | (bf16bits(va.y) << 16);
            pk.y = bf16bits(va.z) | (bf16bits(va.w) << 16);
            pk.z = bf16bits(vb.x) | (bf16bits(vb.y) << 16);
            pk.w = bf16bits(vb.z) | (bf16bits(vb.w) << 16);
            *(uint4*)((char*)XL + j * 640 + ((i16 ^ (j & 7)) << 4)) = pk;
        }
    }
    __syncthreads();

    // ---- compute ----
    f32x4 acc[2][2] = {};
    const ushort* wlane = wf + (size_t)(wn * 2) * 512 + (size_t)lane * 8;

#pragma unroll
    for (int kr = 0; kr < 3; ++kr) {
        const int sj = (mrow + kr) & 7;                // (j&7), mr*16 ≡ 0 mod 8
#pragma unroll
        for (int dc = 0; dc < 10; ++dc) {
            const int kc = kr * 10 + dc;
            bf16x8 a[2];
#pragma unroll
            for (int mr = 0; mr < 2; ++mr) {
                const int j = mr * 16 + mrow + kr;
                a[mr] = *(const bf16x8*)((const char*)XL + j * 640 +
                                         (((dc * 4 + koct) ^ sj) << 4));
            }
            const ushort* wk = wlane + (size_t)kc * 4096;
            bf16x8 b0 = *(const bf16x8*)(wk);
            bf16x8 b1 = *(const bf16x8*)(wk + 512);
#pragma unroll
            for (int mr = 0; mr < 2; ++mr) {
                acc[mr][0] = __builtin_amdgcn_mfma_f32_16x16x32_bf16(a[mr], b0, acc[mr][0], 0, 0, 0);
                acc[mr][1] = __builtin_amdgcn_mfma_f32_16x16x32_bf16(a[mr], b1, acc[mr][1], 0, 0, 0);
            }
        }
    }

    // ---- epilogue -> bf16 feat. C/D layout col=lane&15, row=(lane>>4)*4+r ----
#pragma unroll
    for (int nr = 0; nr < 2; ++nr) {
        const int f = wn * 32 + nr * 16 + mrow;
        const float bias = cb[f];
#pragma unroll
        for (int mr = 0; mr < 2; ++mr) {
            const int lb = l0 + mr * 16 + koct * 4;
#pragma unroll
            for (int r = 0; r < 4; ++r)
                feat[((size_t)b * SEQL + (lb + r)) * FMAPS + f] =
                    (ushort)bf16bits(relu_(acc[mr][nr][r] + bias));
        }
    }
}

// ---------------------------------------------------------------------------
// 3. ROI max-pool + collapsed FC, v3 (bf16 feat, 8 rows in flight).
//    Wave per ROI. lane = rq(2b)|c8(4b): channels c8*8..+7, row offset rq.
//    Integer max is valid: feat is post-ReLU (>=0) bf16 bit patterns.
//    After butterfly, ALL lanes hold the pooled row; the 4 rq-groups each
//    handle 2 classes (c = rq*2 + cc).
// ---------------------------------------------------------------------------
__global__ __launch_bounds__(256) void roi_fc(
    const ushort* __restrict__ feat, const int* __restrict__ rois,
    const int* __restrict__ ridx, const float* __restrict__ Mfp,
    const float* __restrict__ b2, float* __restrict__ out) {
    const int w    = threadIdx.x >> 6;
    const int lane = threadIdx.x & 63;
    const int n    = blockIdx.x * 4 + w;       // 512 blocks * 4 waves = 2048
    const int x1 = rois[n * 2 + 0];
    const int x2 = rois[n * 2 + 1];
    const int bi = ridx[n];
    const int c8 = lane & 15, rq = lane >> 4;

    const ushort* base = feat + (size_t)bi * SEQL * FMAPS + c8 * 8;
    u16x8 mx = (u16x8)0;                       // safe floor: feat >= 0
    for (int l = x1 + rq; l < x2; l += 8) {
        int l2 = min(l + 4, x2 - 1);           // clamp-duplicate: max-idempotent
        u16x8 v1 = *(const u16x8*)(base + (size_t)l  * FMAPS);
        u16x8 v2 = *(const u16x8*)(base + (size_t)l2 * FMAPS);
        mx = umax8(mx, umax8(v1, v2));
    }
    mx = umax8(mx, shfl8(mx, 16));
    mx = umax8(mx, shfl8(mx, 32));             // all lanes now hold pooled max

    float pm[8];
#pragma unroll
    for (int j = 0; j < 8; ++j) pm[j] = __uint_as_float((uint)mx[j] << 16);

#pragma unroll
    for (int cc = 0; cc < 2; ++cc) {
        const int c = rq * 2 + cc;             // group rq handles classes 2rq, 2rq+1
        float4 wa = make_float4(0.f, 0.f, 0.f, 0.f), wb = wa;
#pragma unroll
        for (int q = 0; q < 4; ++q) {
            const float* mrow = Mfp + (size_t)(q * 8 + c) * FMAPS + c8 * 8;
            float4 aq = *(const float4*)mrow;
            float4 bq = *(const float4*)(mrow + 4);
            wa.x += aq.x; wa.y += aq.y; wa.z += aq.z; wa.w += aq.w;
            wb.x += bq.x; wb.y += bq.y; wb.z += bq.z; wb.w += bq.w;
        }
        float p = pm[0] * wa.x + pm[1] * wa.y + pm[2] * wa.z + pm[3] * wa.w
                + pm[4] * wb.x + pm[5] * wb.y + pm[6] * wb.z + pm[7] * wb.w;
#pragma unroll
        for (int off = 1; off <= 8; off <<= 1) p += __shfl_xor(p, off, 64);
        if (c8 == 0) out[n * NCLS + c] = p + b2[c];
    }
}

// ---------------------------------------------------------------------------
extern "C" void kernel_launch(void* const* d_in, const int* in_sizes, int n_in,
                              void* d_out, int out_size, void* d_ws, size_t ws_size,
                              hipStream_t stream) {
    const float* sentence = (const float*)d_in[0];
    const int*   rois     = (const int*)d_in[1];
    const int*   ridx     = (const int*)d_in[2];
    const float* conv_w   = (const float*)d_in[3];
    const float* conv_b   = (const float*)d_in[4];
    const float* fc1_w    = (const float*)d_in[5];
    const float* fc1_b    = (const float*)d_in[6];
    const float* cls_w    = (const float*)d_in[7];
    const float* cls_b    = (const float*)d_in[8];
    float* out = (float*)d_out;

    // workspace carve-up (bytes)
    char* ws = (char*)d_ws;
    ushort* Ft  = (ushort*)ws;                         // 64*512*128 bf16 = 8,388,608 B
    ushort* Wf  = (ushort*)(ws + 8388608);             // 122,880 bf16   = 245,760 B
    float*  Mfp = (float*)(ws + 8388608 + 245760);     // 32*128 f32     = 16,384 B
    float*  b2  = Mfp + 4096;                          // 8 f32

    hipLaunchKernelGGL(prep, dim3(MF_BLOCKS + B2_BLOCKS + WPAD_BLOCKS), dim3(256), 0, stream,
                       conv_w, cls_w, fc1_w, fc1_b, cls_b, Wf, Mfp, b2);
    hipLaunchKernelGGL(conv_mfma, dim3(BATCH * (SEQL / 32)), dim3(256), 0, stream,
                       sentence, Wf, conv_b, Ft);
    hipLaunchKernelGGL(roi_fc, dim3(NROI / 4), dim3(256), 0, stream,
                       Ft, rois, ridx, Mfp, b2, out);
}